// Round 10
// baseline (259.161 us; speedup 1.0000x reference)
//
#include <hip/hip_runtime.h>

// OnLSTMCell fused pipeline for MI355X (gfx950).
// B=8192, input=1024, hidden=1024, level=64, d_in=2048.
// ws layout (bytes), total ~117 MB:
//   A_HI   @ 0          : u16[8192*2048]  (32 MB)   bf16(concat(input,h_prev))
//   A_LO   @ 33554432   : u16[8192*2048]  (32 MB)   bf16 residual (level path precision)
//   W_HI   @ 67108864   : u16[4224*2048]  (16.5 MB) rows 0..4095 gate-interleaved (n=j*4+gate), 4096..4223 = W_level
//   WLEV_LO@ 84410368   : u16[128*2048]   (0.5 MB)
//   PART   @ 84934656   : f32[8][8192][128] (32 MB) split-K partials of level GEMM
//   IH     @ 118489088  : f32[8192*64]    (2 MB)
//   FH     @ 120586240  : f32[8192*64]    (2 MB)

typedef unsigned short u16;
typedef __attribute__((ext_vector_type(8))) short bf16x8;
typedef __attribute__((ext_vector_type(8))) short s8v;
typedef __attribute__((ext_vector_type(4))) float f32x4;
typedef __attribute__((ext_vector_type(4))) float v4f;

#define GLDS(g, l) __builtin_amdgcn_global_load_lds(                      \
    (const __attribute__((address_space(1))) void*)(g),                   \
    (__attribute__((address_space(3))) void*)(l), 16, 0, 0)

__device__ __forceinline__ u16 f2bf(float x) {
  unsigned u = __builtin_bit_cast(unsigned, x);
  u += 0x7FFFu + ((u >> 16) & 1u);
  return (u16)(u >> 16);
}
__device__ __forceinline__ float bf2f(u16 h) {
  unsigned u = ((unsigned)h) << 16;
  return __builtin_bit_cast(float, u);
}
__device__ __forceinline__ float fsig(float x) { return 1.0f / (1.0f + __expf(-x)); }
__device__ __forceinline__ float ftanhf(float x) { float e = __expf(2.0f * x); return 1.0f - 2.0f / (e + 1.0f); }

// ---------------------------------------------------------------- convert ---
__global__ __launch_bounds__(256) void k_convert(
    const float* __restrict__ inp, const float* __restrict__ hprev,
    const float* __restrict__ wl, const float* __restrict__ wlev,
    u16* __restrict__ Ahi, u16* __restrict__ Alo,
    u16* __restrict__ Whi, u16* __restrict__ Wlo)
{
  const int GA = (8192 * 2048) / 8;
  const int GW = (4224 * 2048) / 8;
  for (int gi = blockIdx.x * 256 + threadIdx.x; gi < GA + GW; gi += gridDim.x * 256) {
    if (gi < GA) {
      int e = gi << 3; int row = e >> 11, col = e & 2047;
      const float* src = (col < 1024) ? (inp + row * 1024 + col)
                                      : (hprev + row * 1024 + (col - 1024));
      v4f a = *(const v4f*)src, b = *(const v4f*)(src + 4);
      float vv[8] = {a.x, a.y, a.z, a.w, b.x, b.y, b.z, b.w};
      s8v hi, lo;
#pragma unroll
      for (int j = 0; j < 8; ++j) {
        u16 h = f2bf(vv[j]);
        hi[j] = (short)h;
        lo[j] = (short)f2bf(vv[j] - bf2f(h));
      }
      *(s8v*)(Ahi + e) = hi;
      *(s8v*)(Alo + e) = lo;
    } else {
      int e = (gi - GA) << 3; int n = e >> 11, k = e & 2047;
      const float* src;
      if (n < 4096) { int j = n >> 2, g = n & 3; src = wl + (size_t)((g << 10) | j) * 2048 + k; }
      else          { src = wlev + (size_t)(n - 4096) * 2048 + k; }
      v4f a = *(const v4f*)src, b = *(const v4f*)(src + 4);
      float vv[8] = {a.x, a.y, a.z, a.w, b.x, b.y, b.z, b.w};
      s8v hi, lo;
#pragma unroll
      for (int j = 0; j < 8; ++j) {
        u16 h = f2bf(vv[j]);
        hi[j] = (short)h;
        lo[j] = (short)f2bf(vv[j] - bf2f(h));
      }
      *(s8v*)(Whi + e) = hi;
      if (n >= 4096) *(s8v*)(Wlo + (size_t)(n - 4096) * 2048 + k) = lo;
    }
  }
}

// ----------------------------------------------- level GEMM (split-bf16) ---
__global__ __launch_bounds__(256) void k_gemm_level(
    const u16* __restrict__ Ahi, const u16* __restrict__ Alo,
    const u16* __restrict__ Whi, const u16* __restrict__ Wlo,
    float* __restrict__ part)
{
  __shared__ __align__(16) u16 smem[4 * 8192];
  u16 *Ah = smem, *Al = smem + 8192, *Bh = smem + 16384, *Bl = smem + 24576;
  const int tid = threadIdx.x, lane = tid & 63, wid = tid >> 6;
  const int wm = wid >> 1, wn = wid & 1;
  const int rm = blockIdx.x, s = blockIdx.y;
  const int lrow = lane >> 3, lcolE = (lane & 7) << 3;
  const int c16 = lane & 15, r16 = lane >> 4;
  f32x4 acc[4][4] = {};
  const u16* aBaseH = Ahi + (size_t)(rm << 7) * 2048;
  const u16* aBaseL = Alo + (size_t)(rm << 7) * 2048;
  const u16* bBaseH = Whi + (size_t)4096 * 2048;

  for (int kt = 0; kt < 4; ++kt) {
    const int k0 = (s << 8) + (kt << 6);
#pragma unroll
    for (int q = 0; q < 4; ++q) {
      const int ca = (wid << 2) + q;
      size_t roff = (size_t)((ca << 3) + lrow) * 2048 + k0 + lcolE;
      GLDS(aBaseH + roff, Ah + (ca << 9));
      GLDS(aBaseL + roff, Al + (ca << 9));
      GLDS(bBaseH + roff, Bh + (ca << 9));
      GLDS(Wlo + roff,    Bl + (ca << 9));
    }
    __syncthreads();
#pragma unroll
    for (int ks = 0; ks < 2; ++ks) {
      bf16x8 ah[4], al[4];
#pragma unroll
      for (int i = 0; i < 4; ++i) {
        int off = ((wm << 6) + (i << 4) + c16) * 64 + (ks << 5) + (r16 << 3);
        ah[i] = *(const bf16x8*)(Ah + off);
        al[i] = *(const bf16x8*)(Al + off);
      }
#pragma unroll
      for (int j = 0; j < 4; ++j) {
        int off = ((wn << 6) + (j << 4) + c16) * 64 + (ks << 5) + (r16 << 3);
        bf16x8 bh = *(const bf16x8*)(Bh + off);
        bf16x8 bl = *(const bf16x8*)(Bl + off);
#pragma unroll
        for (int i = 0; i < 4; ++i) {
          acc[i][j] = __builtin_amdgcn_mfma_f32_16x16x32_bf16(ah[i], bh, acc[i][j], 0, 0, 0);
          acc[i][j] = __builtin_amdgcn_mfma_f32_16x16x32_bf16(al[i], bh, acc[i][j], 0, 0, 0);
          acc[i][j] = __builtin_amdgcn_mfma_f32_16x16x32_bf16(ah[i], bl, acc[i][j], 0, 0, 0);
        }
      }
    }
    __syncthreads();
  }
#pragma unroll
  for (int mi = 0; mi < 4; ++mi)
#pragma unroll
    for (int ni = 0; ni < 4; ++ni)
#pragma unroll
      for (int r = 0; r < 4; ++r) {
        int ml = (wm << 6) + (mi << 4) + (r16 << 2) + r;
        int nl = (wn << 6) + (ni << 4) + c16;
        part[(size_t)((s << 13) + (rm << 7) + ml) * 128 + nl] = acc[mi][ni][r];
      }
}

// ------------------------------------------- softmax + cumsums (per row) ---
__global__ __launch_bounds__(256) void k_softmax(
    const float* __restrict__ part, float* __restrict__ ih, float* __restrict__ fh)
{
  const int tid = threadIdx.x, lane = tid & 63, w = tid >> 6;
  const int row = blockIdx.x * 4 + w;
  float vi = 0.f, vf = 0.f;
#pragma unroll
  for (int s = 0; s < 8; ++s) {
    vi += part[(size_t)((s << 13) + row) * 128 + lane];
    vf += part[(size_t)((s << 13) + row) * 128 + 64 + lane];
  }
  float mi = vi, mf = vf;
#pragma unroll
  for (int d = 1; d < 64; d <<= 1) {
    mi = fmaxf(mi, __shfl_xor(mi, d, 64));
    mf = fmaxf(mf, __shfl_xor(mf, d, 64));
  }
  float ei = __expf(vi - mi), ef = __expf(vf - mf);
  float si = ei, sf = ef;
#pragma unroll
  for (int d = 1; d < 64; d <<= 1) {
    si += __shfl_xor(si, d, 64);
    sf += __shfl_xor(sf, d, 64);
  }
  float pi = ei / si, pf = ef / sf;
  float ci = pi, cf = pf;
#pragma unroll
  for (int d = 1; d < 64; d <<= 1) {
    float t = __shfl_up(ci, d, 64); if (lane >= d) ci += t;
    float u = __shfl_up(cf, d, 64); if (lane >= d) cf += u;
  }
  ih[(row << 6) + lane] = 1.0f - (ci - pi);
  fh[(row << 6) + lane] = cf;
}

// -------------------------------------- main gates GEMM + fused epilogue ---
// r5's engine + r9's proven block-order (THE one-line fix vs r5).
// 256x128 tile, 512 threads = 8 waves (2M x 4N), wave-tile 128x32 (acc=64
// regs, VGPR ~64 -> 4 waves/SIMD cap). LDS: 3 slots x (A 256x32 + B 128x32)
// = 72 KB -> 2 blocks/CU resident. TLP theory: two blocks' lockstep phases
// are mutually unsynchronized -> block A's ds_read/barrier phases overlap
// block B's MFMA phases on the same CU (m114 mechanism) — breaking the
// 1-block/CU LDS<->MFMA serialization that pinned r2..r9 at 26-30% util.
// One phase per K-slice: {10 ds_read (slot s%3); 3 GLDS stage(s+2);
// vmcnt(3); barrier; lgkmcnt(0); setprio(1); 16 MFMA; setprio(0); barrier}.
// vmcnt ledger (per wave, 3 loads/stage): at vmcnt(3) of slice s the
// outstanding set is {stage(s+1), stage(s+2)} -> forces stage(s+1) complete
// BEFORE this slice's barriers, which precede every wave's slice-(s+1)
// reads => cross-wave safe. WAR: stage(s+2) overwrites slot (s-1)%3, whose
// reads all completed before slice-(s-1)'s lgkmcnt(0)+end-barrier. Never
// vmcnt(0) in-loop. Unroll-3 (compile-time slots), peeled slice 63.
__global__ __launch_bounds__(512, 4) void k_gemm_main(
    const u16* __restrict__ Ab, const u16* __restrict__ Wb,
    const float* __restrict__ cprev, const float* __restrict__ ihp,
    const float* __restrict__ fhp, float* __restrict__ out)
{
  __shared__ __align__(16) u16 smem[36864];        // 72 KB; epi reuses 64 KB
  const int tid = threadIdx.x, lane = tid & 63, wid = tid >> 6;
  const int wm = wid >> 2, wn = wid & 3;           // 2 x 4 wave grid
  const int c16 = lane & 15, r16 = lane >> 4;

  // cm-FAST XCD swizzle (r3/r9-proven locality; r5's rm-fast was the bug):
  // 1024 blocks = 8 XCD x 128 = 4 rm-panels (4 MB A, L2-resident, 32x
  // reuse) x 32 cm (W streamed, L3-absorbed).
  const int bx = blockIdx.x;
  const int nb = (bx & 7) * 128 + (bx >> 3);
  const int rm = nb >> 5, cm = nb & 31;            // rm slow, cm fast

  // staging: thread -> (row sr=tid>>2, 16B slot slq=tid&3); global source
  // pre-permuted (slq ^ (sr>>1)&3) so linear GLDS dest gets the swizzle.
  const int sr = tid >> 2;                          // 0..127
  const int slq = tid & 3;
  const int xk = (slq ^ ((sr >> 1) & 3)) << 3;
  const u16* pa = Ab + (size_t)(rm * 256 + sr) * 2048 + xk;
  const u16* pb = Wb + (size_t)(cm * 128 + sr) * 2048 + xk;
  char* const ldsW = (char*)smem + (wid << 10);     // wave segment (1 KB)

  // ds_read offsets (u16 elements): slot base + row*32 + swizzled 16B slot.
  const int xsl = (r16 ^ ((c16 >> 1) & 3)) << 3;
  const int base_a = (wm * 128 + c16) * 32 + xsl;   // + i*512 (i=0..7)
  const int base_b = 8192 + (wn * 32 + c16) * 32 + xsl; // + j*512 (j=0..1)

  f32x4 acc[8][2] = {};

#define STAGE3(slice, slot) do {                                       \
    const u16* sa_ = pa + (slice) * 32;                                \
    const u16* sb_ = pb + (slice) * 32;                                \
    char* d_ = ldsW + (slot) * 24576;                                  \
    GLDS(sa_, d_); GLDS(sa_ + 262144, d_ + 8192);                      \
    GLDS(sb_, d_ + 16384);                                             \
  } while (0)

#define SLICE(s, slot, dostage) do {                                   \
    bf16x8 aX[8], bS[2];                                               \
    _Pragma("unroll")                                                  \
    for (int i = 0; i < 8; ++i)                                        \
      aX[i] = *(const bf16x8*)(smem + (slot) * 12288 + base_a + i * 512); \
    _Pragma("unroll")                                                  \
    for (int j = 0; j < 2; ++j)                                        \
      bS[j] = *(const bf16x8*)(smem + (slot) * 12288 + base_b + j * 512); \
    if (dostage) STAGE3(((s) + 2) & 63, ((s) + 2) % 3);                \
    asm volatile("s_waitcnt vmcnt(3)" ::: "memory");                   \
    __builtin_amdgcn_s_barrier();                                      \
    asm volatile("s_waitcnt lgkmcnt(0)" ::: "memory");                 \
    __builtin_amdgcn_s_setprio(1);                                     \
    _Pragma("unroll")                                                  \
    for (int i = 0; i < 8; ++i)                                        \
      _Pragma("unroll")                                                \
      for (int j = 0; j < 2; ++j)                                      \
        acc[i][j] = __builtin_amdgcn_mfma_f32_16x16x32_bf16(           \
            aX[i], bS[j], acc[i][j], 0, 0, 0);                         \
    __builtin_amdgcn_s_setprio(0);                                     \
    __builtin_amdgcn_s_barrier();                                      \
  } while (0)

  // prologue: slices 0,1 -> slots 0,1; vmcnt(3) forces slice 0 complete
  // (leaves slice 1 in flight); barrier publishes to all waves.
  STAGE3(0, 0); STAGE3(1, 1);
  asm volatile("s_waitcnt vmcnt(3)" ::: "memory");
  __builtin_amdgcn_s_barrier();

  for (int u = 0; u < 21; ++u) {                    // slices 0..62
    const int s0 = u * 3;
    SLICE(s0 + 0, 0, 1);
    SLICE(s0 + 1, 1, 1);
    SLICE(s0 + 2, 2, 1);
  }
  SLICE(63, 0, 0);                                  // peeled last slice
#undef SLICE
#undef STAGE3

  // drain wrap-dummy stages before LDS reuse
  asm volatile("s_waitcnt vmcnt(0)" ::: "memory");
  __builtin_amdgcn_s_barrier();

  // ---- fused ON-LSTM epilogue: 2 passes, epi = f32[256][64] (64 KB) ----
  float* epi = (float*)smem;
  for (int p = 0; p < 2; ++p) {
    if ((wn >> 1) == p) {
#pragma unroll
      for (int i = 0; i < 8; ++i)
#pragma unroll
        for (int j = 0; j < 2; ++j)
#pragma unroll
          for (int r = 0; r < 4; ++r) {
            int rowl = wm * 128 + i * 16 + r16 * 4 + r;
            int coll = (wn & 1) * 32 + j * 16 + c16;
            float v = acc[i][j][r];
            v = ((c16 & 3) == 3) ? ftanhf(v) : fsig(v);
            epi[rowl * 64 + coll] = v;
          }
    }
    __syncthreads();
#pragma unroll
    for (int e = 0; e < 8; ++e) {
      int idx = (e << 9) + tid;
      int m = idx >> 4, jl = idx & 15;
      v4f v = *(const v4f*)(epi + m * 64 + (jl << 2));   // i,f,o,g (activated)
      int rowg = rm * 256 + m;
      int jg = cm * 32 + p * 16 + jl;                    // hidden index 0..1023
      float cp = cprev[rowg * 1024 + jg];
      int lv = jg >> 4;
      float vih = ihp[(rowg << 6) + lv], vfh = fhp[(rowg << 6) + lv];
      float iv = v.x, fv = v.y, ov = v.z, gv = v.w;
      float wq = vih * vfh;
      float c = wq * (fv * cp + iv * gv) + (vfh - wq) * cp + (vih - wq) * gv;
      float h = ov * ftanhf(c);
      out[rowg * 1024 + jg] = h;
      out[8388608 + rowg * 1024 + jg] = c;
    }
    __syncthreads();
  }
}

// -------------------------------------------------------------- launcher ---
extern "C" void kernel_launch(void* const* d_in, const int* in_sizes, int n_in,
                              void* d_out, int out_size, void* d_ws, size_t ws_size,
                              hipStream_t stream) {
  (void)in_sizes; (void)n_in; (void)out_size; (void)ws_size;
  const float* inp   = (const float*)d_in[0];
  const float* hprev = (const float*)d_in[1];
  const float* cprev = (const float*)d_in[2];
  const float* wl    = (const float*)d_in[3];
  const float* wlev  = (const float*)d_in[4];
  float* out = (float*)d_out;
  char* ws = (char*)d_ws;

  u16* Ahi  = (u16*)(ws);
  u16* Alo  = (u16*)(ws + 33554432);
  u16* Whi  = (u16*)(ws + 67108864);
  u16* Wlo  = (u16*)(ws + 84410368);
  float* part = (float*)(ws + 84934656);
  float* ih   = (float*)(ws + 118489088);
  float* fh   = (float*)(ws + 120586240);

  k_convert<<<dim3(2048), dim3(256), 0, stream>>>(inp, hprev, wl, wlev, Ahi, Alo, Whi, Wlo);
  k_gemm_level<<<dim3(64, 8), dim3(256), 0, stream>>>(Ahi, Alo, Whi, Wlo, part);
  k_softmax<<<dim3(2048), dim3(256), 0, stream>>>(part, ih, fh);
  k_gemm_main<<<dim3(1024), dim3(512), 0, stream>>>(Ahi, Whi, cprev, ih, fh, out);
}

// Round 11
// 224.154 us; speedup vs baseline: 1.1562x; 1.1562x over previous
//
#include <hip/hip_runtime.h>

// OnLSTMCell fused pipeline for MI355X (gfx950).
// B=8192, input=1024, hidden=1024, level=64, d_in=2048.
// ws layout (bytes), total ~117 MB:
//   A_HI   @ 0          : u16[8192*2048]  (32 MB)   bf16(concat(input,h_prev))
//   A_LO   @ 33554432   : u16[8192*2048]  (32 MB)   bf16 residual (level path precision)
//   W_HI   @ 67108864   : u16[4224*2048]  (16.5 MB) rows 0..4095 gate-interleaved (n=j*4+gate), 4096..4223 = W_level
//   WLEV_LO@ 84410368   : u16[128*2048]   (0.5 MB)
//   PART   @ 84934656   : f32[8][8192][128] (32 MB) split-K partials of level GEMM
//   IH     @ 118489088  : f32[8192*64]    (2 MB)
//   FH     @ 120586240  : f32[8192*64]    (2 MB)

typedef unsigned short u16;
typedef __attribute__((ext_vector_type(8))) short bf16x8;
typedef __attribute__((ext_vector_type(8))) short s8v;
typedef __attribute__((ext_vector_type(4))) float f32x4;
typedef __attribute__((ext_vector_type(4))) float v4f;

#define GLDS(g, l) __builtin_amdgcn_global_load_lds(                      \
    (const __attribute__((address_space(1))) void*)(g),                   \
    (__attribute__((address_space(3))) void*)(l), 16, 0, 0)

__device__ __forceinline__ u16 f2bf(float x) {
  unsigned u = __builtin_bit_cast(unsigned, x);
  u += 0x7FFFu + ((u >> 16) & 1u);
  return (u16)(u >> 16);
}
__device__ __forceinline__ float bf2f(u16 h) {
  unsigned u = ((unsigned)h) << 16;
  return __builtin_bit_cast(float, u);
}
__device__ __forceinline__ float fsig(float x) { return 1.0f / (1.0f + __expf(-x)); }
__device__ __forceinline__ float ftanhf(float x) { float e = __expf(2.0f * x); return 1.0f - 2.0f / (e + 1.0f); }

// ---------------------------------------------------------------- convert ---
__global__ __launch_bounds__(256) void k_convert(
    const float* __restrict__ inp, const float* __restrict__ hprev,
    const float* __restrict__ wl, const float* __restrict__ wlev,
    u16* __restrict__ Ahi, u16* __restrict__ Alo,
    u16* __restrict__ Whi, u16* __restrict__ Wlo)
{
  const int GA = (8192 * 2048) / 8;
  const int GW = (4224 * 2048) / 8;
  for (int gi = blockIdx.x * 256 + threadIdx.x; gi < GA + GW; gi += gridDim.x * 256) {
    if (gi < GA) {
      int e = gi << 3; int row = e >> 11, col = e & 2047;
      const float* src = (col < 1024) ? (inp + row * 1024 + col)
                                      : (hprev + row * 1024 + (col - 1024));
      v4f a = *(const v4f*)src, b = *(const v4f*)(src + 4);
      float vv[8] = {a.x, a.y, a.z, a.w, b.x, b.y, b.z, b.w};
      s8v hi, lo;
#pragma unroll
      for (int j = 0; j < 8; ++j) {
        u16 h = f2bf(vv[j]);
        hi[j] = (short)h;
        lo[j] = (short)f2bf(vv[j] - bf2f(h));
      }
      *(s8v*)(Ahi + e) = hi;
      *(s8v*)(Alo + e) = lo;
    } else {
      int e = (gi - GA) << 3; int n = e >> 11, k = e & 2047;
      const float* src;
      if (n < 4096) { int j = n >> 2, g = n & 3; src = wl + (size_t)((g << 10) | j) * 2048 + k; }
      else          { src = wlev + (size_t)(n - 4096) * 2048 + k; }
      v4f a = *(const v4f*)src, b = *(const v4f*)(src + 4);
      float vv[8] = {a.x, a.y, a.z, a.w, b.x, b.y, b.z, b.w};
      s8v hi, lo;
#pragma unroll
      for (int j = 0; j < 8; ++j) {
        u16 h = f2bf(vv[j]);
        hi[j] = (short)h;
        lo[j] = (short)f2bf(vv[j] - bf2f(h));
      }
      *(s8v*)(Whi + e) = hi;
      if (n >= 4096) *(s8v*)(Wlo + (size_t)(n - 4096) * 2048 + k) = lo;
    }
  }
}

// ----------------------------------------------- level GEMM (split-bf16) ---
__global__ __launch_bounds__(256) void k_gemm_level(
    const u16* __restrict__ Ahi, const u16* __restrict__ Alo,
    const u16* __restrict__ Whi, const u16* __restrict__ Wlo,
    float* __restrict__ part)
{
  __shared__ __align__(16) u16 smem[4 * 8192];
  u16 *Ah = smem, *Al = smem + 8192, *Bh = smem + 16384, *Bl = smem + 24576;
  const int tid = threadIdx.x, lane = tid & 63, wid = tid >> 6;
  const int wm = wid >> 1, wn = wid & 1;
  const int rm = blockIdx.x, s = blockIdx.y;
  const int lrow = lane >> 3, lcolE = (lane & 7) << 3;
  const int c16 = lane & 15, r16 = lane >> 4;
  f32x4 acc[4][4] = {};
  const u16* aBaseH = Ahi + (size_t)(rm << 7) * 2048;
  const u16* aBaseL = Alo + (size_t)(rm << 7) * 2048;
  const u16* bBaseH = Whi + (size_t)4096 * 2048;

  for (int kt = 0; kt < 4; ++kt) {
    const int k0 = (s << 8) + (kt << 6);
#pragma unroll
    for (int q = 0; q < 4; ++q) {
      const int ca = (wid << 2) + q;
      size_t roff = (size_t)((ca << 3) + lrow) * 2048 + k0 + lcolE;
      GLDS(aBaseH + roff, Ah + (ca << 9));
      GLDS(aBaseL + roff, Al + (ca << 9));
      GLDS(bBaseH + roff, Bh + (ca << 9));
      GLDS(Wlo + roff,    Bl + (ca << 9));
    }
    __syncthreads();
#pragma unroll
    for (int ks = 0; ks < 2; ++ks) {
      bf16x8 ah[4], al[4];
#pragma unroll
      for (int i = 0; i < 4; ++i) {
        int off = ((wm << 6) + (i << 4) + c16) * 64 + (ks << 5) + (r16 << 3);
        ah[i] = *(const bf16x8*)(Ah + off);
        al[i] = *(const bf16x8*)(Al + off);
      }
#pragma unroll
      for (int j = 0; j < 4; ++j) {
        int off = ((wn << 6) + (j << 4) + c16) * 64 + (ks << 5) + (r16 << 3);
        bf16x8 bh = *(const bf16x8*)(Bh + off);
        bf16x8 bl = *(const bf16x8*)(Bl + off);
#pragma unroll
        for (int i = 0; i < 4; ++i) {
          acc[i][j] = __builtin_amdgcn_mfma_f32_16x16x32_bf16(ah[i], bh, acc[i][j], 0, 0, 0);
          acc[i][j] = __builtin_amdgcn_mfma_f32_16x16x32_bf16(al[i], bh, acc[i][j], 0, 0, 0);
          acc[i][j] = __builtin_amdgcn_mfma_f32_16x16x32_bf16(ah[i], bl, acc[i][j], 0, 0, 0);
        }
      }
    }
    __syncthreads();
  }
#pragma unroll
  for (int mi = 0; mi < 4; ++mi)
#pragma unroll
    for (int ni = 0; ni < 4; ++ni)
#pragma unroll
      for (int r = 0; r < 4; ++r) {
        int ml = (wm << 6) + (mi << 4) + (r16 << 2) + r;
        int nl = (wn << 6) + (ni << 4) + c16;
        part[(size_t)((s << 13) + (rm << 7) + ml) * 128 + nl] = acc[mi][ni][r];
      }
}

// ------------------------------------------- softmax + cumsums (per row) ---
__global__ __launch_bounds__(256) void k_softmax(
    const float* __restrict__ part, float* __restrict__ ih, float* __restrict__ fh)
{
  const int tid = threadIdx.x, lane = tid & 63, w = tid >> 6;
  const int row = blockIdx.x * 4 + w;
  float vi = 0.f, vf = 0.f;
#pragma unroll
  for (int s = 0; s < 8; ++s) {
    vi += part[(size_t)((s << 13) + row) * 128 + lane];
    vf += part[(size_t)((s << 13) + row) * 128 + 64 + lane];
  }
  float mi = vi, mf = vf;
#pragma unroll
  for (int d = 1; d < 64; d <<= 1) {
    mi = fmaxf(mi, __shfl_xor(mi, d, 64));
    mf = fmaxf(mf, __shfl_xor(mf, d, 64));
  }
  float ei = __expf(vi - mi), ef = __expf(vf - mf);
  float si = ei, sf = ef;
#pragma unroll
  for (int d = 1; d < 64; d <<= 1) {
    si += __shfl_xor(si, d, 64);
    sf += __shfl_xor(sf, d, 64);
  }
  float pi = ei / si, pf = ef / sf;
  float ci = pi, cf = pf;
#pragma unroll
  for (int d = 1; d < 64; d <<= 1) {
    float t = __shfl_up(ci, d, 64); if (lane >= d) ci += t;
    float u = __shfl_up(cf, d, 64); if (lane >= d) cf += u;
  }
  ih[(row << 6) + lane] = 1.0f - (ci - pi);
  fh[(row << 6) + lane] = cf;
}

// -------------------------------------- main gates GEMM + fused epilogue ---
// r10 structure (256x128 tile, 8 waves 2Mx4N, 3-slot 72KB LDS, 2 blocks/CU,
// cm-fast XCD map, proven vmcnt(3) ledger) with TWO changes:
//  (1) NO setprio. Theory: with 4 waves/SIMD from 2 independent blocks,
//      prio-1 MFMA waves starved the other block's prio-0 ds_read issue,
//      phase-locking the blocks (r10: MfmaUtil 29% = serialized pipes;
//      m190 measured setprio negative on multi-block structures).
//  (2) Coalesced epilogue: epi[128][128] f32 (64 KB), 2 row-passes, v4f
//      stores -> 128-B contiguous lines (r10's 64-B segments caused 2.4x
//      write amplification: 158 MB vs 64 MB ideal).
__global__ __launch_bounds__(512, 4) void k_gemm_main(
    const u16* __restrict__ Ab, const u16* __restrict__ Wb,
    const float* __restrict__ cprev, const float* __restrict__ ihp,
    const float* __restrict__ fhp, float* __restrict__ out)
{
  __shared__ __align__(16) u16 smem[36864];        // 72 KB; epi reuses 64 KB
  const int tid = threadIdx.x, lane = tid & 63, wid = tid >> 6;
  const int wm = wid >> 2, wn = wid & 3;           // 2 x 4 wave grid
  const int c16 = lane & 15, r16 = lane >> 4;

  // cm-FAST XCD swizzle (r3/r9-proven): 1024 blocks = 8 XCD x 128 =
  // 4 rm-panels (A L2-resident) x 32 cm (W streamed, L3-absorbed).
  const int bx = blockIdx.x;
  const int nb = (bx & 7) * 128 + (bx >> 3);
  const int rm = nb >> 5, cm = nb & 31;            // rm slow, cm fast

  // staging: thread -> (row sr=tid>>2, 16B slot slq=tid&3); global source
  // pre-permuted (slq ^ (sr>>1)&3) so linear GLDS dest gets the swizzle.
  const int sr = tid >> 2;                          // 0..127
  const int slq = tid & 3;
  const int xk = (slq ^ ((sr >> 1) & 3)) << 3;
  const u16* pa = Ab + (size_t)(rm * 256 + sr) * 2048 + xk;
  const u16* pb = Wb + (size_t)(cm * 128 + sr) * 2048 + xk;
  char* const ldsW = (char*)smem + (wid << 10);     // wave segment (1 KB)

  // ds_read offsets (u16 elements): slot base + row*32 + swizzled 16B slot.
  const int xsl = (r16 ^ ((c16 >> 1) & 3)) << 3;
  const int base_a = (wm * 128 + c16) * 32 + xsl;   // + i*512 (i=0..7)
  const int base_b = 8192 + (wn * 32 + c16) * 32 + xsl; // + j*512 (j=0..1)

  f32x4 acc[8][2] = {};

#define STAGE3(slice, slot) do {                                       \
    const u16* sa_ = pa + (slice) * 32;                                \
    const u16* sb_ = pb + (slice) * 32;                                \
    char* d_ = ldsW + (slot) * 24576;                                  \
    GLDS(sa_, d_); GLDS(sa_ + 262144, d_ + 8192);                      \
    GLDS(sb_, d_ + 16384);                                             \
  } while (0)

#define SLICE(s, slot, dostage) do {                                   \
    bf16x8 aX[8], bS[2];                                               \
    _Pragma("unroll")                                                  \
    for (int i = 0; i < 8; ++i)                                        \
      aX[i] = *(const bf16x8*)(smem + (slot) * 12288 + base_a + i * 512); \
    _Pragma("unroll")                                                  \
    for (int j = 0; j < 2; ++j)                                        \
      bS[j] = *(const bf16x8*)(smem + (slot) * 12288 + base_b + j * 512); \
    if (dostage) STAGE3(((s) + 2) & 63, ((s) + 2) % 3);                \
    asm volatile("s_waitcnt vmcnt(3)" ::: "memory");                   \
    __builtin_amdgcn_s_barrier();                                      \
    asm volatile("s_waitcnt lgkmcnt(0)" ::: "memory");                 \
    _Pragma("unroll")                                                  \
    for (int i = 0; i < 8; ++i)                                        \
      _Pragma("unroll")                                                \
      for (int j = 0; j < 2; ++j)                                      \
        acc[i][j] = __builtin_amdgcn_mfma_f32_16x16x32_bf16(           \
            aX[i], bS[j], acc[i][j], 0, 0, 0);                         \
    __builtin_amdgcn_s_barrier();                                      \
  } while (0)

  // prologue: slices 0,1 -> slots 0,1; vmcnt(3) forces slice 0 complete
  // (leaves slice 1 in flight); barrier publishes to all waves.
  STAGE3(0, 0); STAGE3(1, 1);
  asm volatile("s_waitcnt vmcnt(3)" ::: "memory");
  __builtin_amdgcn_s_barrier();

  for (int u = 0; u < 21; ++u) {                    // slices 0..62
    const int s0 = u * 3;
    SLICE(s0 + 0, 0, 1);
    SLICE(s0 + 1, 1, 1);
    SLICE(s0 + 2, 2, 1);
  }
  SLICE(63, 0, 0);                                  // peeled last slice
#undef SLICE
#undef STAGE3

  // drain wrap-dummy stages before LDS reuse
  asm volatile("s_waitcnt vmcnt(0)" ::: "memory");
  __builtin_amdgcn_s_barrier();

  // ---- fused ON-LSTM epilogue: 2 row-passes, epi = f32[128][128] (64 KB).
  // Pass p: waves wm==p write rows p*128..p*128+127 (all 128 gate-cols);
  // then all threads compute 4 consecutive hidden units each and store
  // v4f h and c -> 128-B contiguous aligned lines (8 threads/row).
  float* epi = (float*)smem;
#define EPIPASS(p) do {                                                \
    if (wm == (p)) {                                                   \
      _Pragma("unroll")                                                \
      for (int i = 0; i < 8; ++i)                                      \
        _Pragma("unroll")                                              \
        for (int j = 0; j < 2; ++j)                                    \
          _Pragma("unroll")                                            \
          for (int r = 0; r < 4; ++r) {                                \
            float v = acc[i][j][r];                                    \
            v = ((c16 & 3) == 3) ? ftanhf(v) : fsig(v);                \
            epi[(i * 16 + r16 * 4 + r) * 128 + wn * 32 + j * 16 + c16] = v; \
          }                                                            \
    }                                                                  \
    __syncthreads();                                                   \
    _Pragma("unroll")                                                  \
    for (int e = 0; e < 2; ++e) {                                      \
      int idx = (e << 9) + tid;                                        \
      int mrow = idx >> 3, q = idx & 7;                                \
      const float* g4 = epi + mrow * 128 + q * 16;                     \
      int rowg = rm * 256 + (p) * 128 + mrow;                          \
      int jgb = cm * 32 + q * 4;                                       \
      int lv = jgb >> 4;                                               \
      float vih = ihp[(rowg << 6) + lv], vfh = fhp[(rowg << 6) + lv];  \
      float wq = vih * vfh;                                            \
      v4f cp4 = *(const v4f*)(cprev + rowg * 1024 + jgb);              \
      float cpv[4] = {cp4.x, cp4.y, cp4.z, cp4.w};                     \
      v4f hv, cv;                                                      \
      _Pragma("unroll")                                                \
      for (int t = 0; t < 4; ++t) {                                    \
        v4f g = *(const v4f*)(g4 + t * 4);                             \
        float iv = g.x, fv = g.y, ov = g.z, gv = g.w;                  \
        float cpx = cpv[t];                                            \
        float c = wq * (fv * cpx + iv * gv) + (vfh - wq) * cpx + (vih - wq) * gv; \
        float h = ov * ftanhf(c);                                      \
        hv[t] = h; cv[t] = c;                                          \
      }                                                                \
      *(v4f*)(out + rowg * 1024 + jgb) = hv;                           \
      *(v4f*)(out + 8388608 + rowg * 1024 + jgb) = cv;                 \
    }                                                                  \
    __syncthreads();                                                   \
  } while (0)
  EPIPASS(0); EPIPASS(1);
#undef EPIPASS
}

// -------------------------------------------------------------- launcher ---
extern "C" void kernel_launch(void* const* d_in, const int* in_sizes, int n_in,
                              void* d_out, int out_size, void* d_ws, size_t ws_size,
                              hipStream_t stream) {
  (void)in_sizes; (void)n_in; (void)out_size; (void)ws_size;
  const float* inp   = (const float*)d_in[0];
  const float* hprev = (const float*)d_in[1];
  const float* cprev = (const float*)d_in[2];
  const float* wl    = (const float*)d_in[3];
  const float* wlev  = (const float*)d_in[4];
  float* out = (float*)d_out;
  char* ws = (char*)d_ws;

  u16* Ahi  = (u16*)(ws);
  u16* Alo  = (u16*)(ws + 33554432);
  u16* Whi  = (u16*)(ws + 67108864);
  u16* Wlo  = (u16*)(ws + 84410368);
  float* part = (float*)(ws + 84934656);
  float* ih   = (float*)(ws + 118489088);
  float* fh   = (float*)(ws + 120586240);

  k_convert<<<dim3(2048), dim3(256), 0, stream>>>(inp, hprev, wl, wlev, Ahi, Alo, Whi, Wlo);
  k_gemm_level<<<dim3(64, 8), dim3(256), 0, stream>>>(Ahi, Alo, Whi, Wlo, part);
  k_softmax<<<dim3(2048), dim3(256), 0, stream>>>(part, ih, fh);
  k_gemm_main<<<dim3(1024), dim3(512), 0, stream>>>(Ahi, Whi, cprev, ih, fh, out);
}

// Round 12
// 219.565 us; speedup vs baseline: 1.1803x; 1.0209x over previous
//
#include <hip/hip_runtime.h>

// OnLSTMCell fused pipeline for MI355X (gfx950).
// B=8192, input=1024, hidden=1024, level=64, d_in=2048.
// ws layout (bytes), total ~117 MB:
//   A_HI   @ 0          : u16[8192*2048]  (32 MB)   bf16(concat(input,h_prev))
//   A_LO   @ 33554432   : u16[8192*2048]  (32 MB)   bf16 residual (level path precision)
//   W_HI   @ 67108864   : u16[4224*2048]  (16.5 MB) rows 0..4095 gate-interleaved (n=j*4+gate), 4096..4223 = W_level
//   WLEV_LO@ 84410368   : u16[128*2048]   (0.5 MB)
//   PART   @ 84934656   : f32[8][8192][128] (32 MB) split-K partials of level GEMM
//   IH     @ 118489088  : f32[8192*64]    (2 MB)
//   FH     @ 120586240  : f32[8192*64]    (2 MB)

typedef unsigned short u16;
typedef __attribute__((ext_vector_type(8))) short bf16x8;
typedef __attribute__((ext_vector_type(8))) short s8v;
typedef __attribute__((ext_vector_type(4))) float f32x4;
typedef __attribute__((ext_vector_type(4))) float v4f;

#define GLDS(g, l) __builtin_amdgcn_global_load_lds(                      \
    (const __attribute__((address_space(1))) void*)(g),                   \
    (__attribute__((address_space(3))) void*)(l), 16, 0, 0)

__device__ __forceinline__ u16 f2bf(float x) {
  unsigned u = __builtin_bit_cast(unsigned, x);
  u += 0x7FFFu + ((u >> 16) & 1u);
  return (u16)(u >> 16);
}
__device__ __forceinline__ float bf2f(u16 h) {
  unsigned u = ((unsigned)h) << 16;
  return __builtin_bit_cast(float, u);
}
__device__ __forceinline__ float fsig(float x) { return 1.0f / (1.0f + __expf(-x)); }
__device__ __forceinline__ float ftanhf(float x) { float e = __expf(2.0f * x); return 1.0f - 2.0f / (e + 1.0f); }

// ---------------------------------------------------------------- convert ---
__global__ __launch_bounds__(256) void k_convert(
    const float* __restrict__ inp, const float* __restrict__ hprev,
    const float* __restrict__ wl, const float* __restrict__ wlev,
    u16* __restrict__ Ahi, u16* __restrict__ Alo,
    u16* __restrict__ Whi, u16* __restrict__ Wlo)
{
  const int GA = (8192 * 2048) / 8;
  const int GW = (4224 * 2048) / 8;
  for (int gi = blockIdx.x * 256 + threadIdx.x; gi < GA + GW; gi += gridDim.x * 256) {
    if (gi < GA) {
      int e = gi << 3; int row = e >> 11, col = e & 2047;
      const float* src = (col < 1024) ? (inp + row * 1024 + col)
                                      : (hprev + row * 1024 + (col - 1024));
      v4f a = *(const v4f*)src, b = *(const v4f*)(src + 4);
      float vv[8] = {a.x, a.y, a.z, a.w, b.x, b.y, b.z, b.w};
      s8v hi, lo;
#pragma unroll
      for (int j = 0; j < 8; ++j) {
        u16 h = f2bf(vv[j]);
        hi[j] = (short)h;
        lo[j] = (short)f2bf(vv[j] - bf2f(h));
      }
      *(s8v*)(Ahi + e) = hi;
      *(s8v*)(Alo + e) = lo;
    } else {
      int e = (gi - GA) << 3; int n = e >> 11, k = e & 2047;
      const float* src;
      if (n < 4096) { int j = n >> 2, g = n & 3; src = wl + (size_t)((g << 10) | j) * 2048 + k; }
      else          { src = wlev + (size_t)(n - 4096) * 2048 + k; }
      v4f a = *(const v4f*)src, b = *(const v4f*)(src + 4);
      float vv[8] = {a.x, a.y, a.z, a.w, b.x, b.y, b.z, b.w};
      s8v hi, lo;
#pragma unroll
      for (int j = 0; j < 8; ++j) {
        u16 h = f2bf(vv[j]);
        hi[j] = (short)h;
        lo[j] = (short)f2bf(vv[j] - bf2f(h));
      }
      *(s8v*)(Whi + e) = hi;
      if (n >= 4096) *(s8v*)(Wlo + (size_t)(n - 4096) * 2048 + k) = lo;
    }
  }
}

// ----------------------------------------------- level GEMM (split-bf16) ---
__global__ __launch_bounds__(256) void k_gemm_level(
    const u16* __restrict__ Ahi, const u16* __restrict__ Alo,
    const u16* __restrict__ Whi, const u16* __restrict__ Wlo,
    float* __restrict__ part)
{
  __shared__ __align__(16) u16 smem[4 * 8192];
  u16 *Ah = smem, *Al = smem + 8192, *Bh = smem + 16384, *Bl = smem + 24576;
  const int tid = threadIdx.x, lane = tid & 63, wid = tid >> 6;
  const int wm = wid >> 1, wn = wid & 1;
  const int rm = blockIdx.x, s = blockIdx.y;
  const int lrow = lane >> 3, lcolE = (lane & 7) << 3;
  const int c16 = lane & 15, r16 = lane >> 4;
  f32x4 acc[4][4] = {};
  const u16* aBaseH = Ahi + (size_t)(rm << 7) * 2048;
  const u16* aBaseL = Alo + (size_t)(rm << 7) * 2048;
  const u16* bBaseH = Whi + (size_t)4096 * 2048;

  for (int kt = 0; kt < 4; ++kt) {
    const int k0 = (s << 8) + (kt << 6);
#pragma unroll
    for (int q = 0; q < 4; ++q) {
      const int ca = (wid << 2) + q;
      size_t roff = (size_t)((ca << 3) + lrow) * 2048 + k0 + lcolE;
      GLDS(aBaseH + roff, Ah + (ca << 9));
      GLDS(aBaseL + roff, Al + (ca << 9));
      GLDS(bBaseH + roff, Bh + (ca << 9));
      GLDS(Wlo + roff,    Bl + (ca << 9));
    }
    __syncthreads();
#pragma unroll
    for (int ks = 0; ks < 2; ++ks) {
      bf16x8 ah[4], al[4];
#pragma unroll
      for (int i = 0; i < 4; ++i) {
        int off = ((wm << 6) + (i << 4) + c16) * 64 + (ks << 5) + (r16 << 3);
        ah[i] = *(const bf16x8*)(Ah + off);
        al[i] = *(const bf16x8*)(Al + off);
      }
#pragma unroll
      for (int j = 0; j < 4; ++j) {
        int off = ((wn << 6) + (j << 4) + c16) * 64 + (ks << 5) + (r16 << 3);
        bf16x8 bh = *(const bf16x8*)(Bh + off);
        bf16x8 bl = *(const bf16x8*)(Bl + off);
#pragma unroll
        for (int i = 0; i < 4; ++i) {
          acc[i][j] = __builtin_amdgcn_mfma_f32_16x16x32_bf16(ah[i], bh, acc[i][j], 0, 0, 0);
          acc[i][j] = __builtin_amdgcn_mfma_f32_16x16x32_bf16(al[i], bh, acc[i][j], 0, 0, 0);
          acc[i][j] = __builtin_amdgcn_mfma_f32_16x16x32_bf16(ah[i], bl, acc[i][j], 0, 0, 0);
        }
      }
    }
    __syncthreads();
  }
#pragma unroll
  for (int mi = 0; mi < 4; ++mi)
#pragma unroll
    for (int ni = 0; ni < 4; ++ni)
#pragma unroll
      for (int r = 0; r < 4; ++r) {
        int ml = (wm << 6) + (mi << 4) + (r16 << 2) + r;
        int nl = (wn << 6) + (ni << 4) + c16;
        part[(size_t)((s << 13) + (rm << 7) + ml) * 128 + nl] = acc[mi][ni][r];
      }
}

// ------------------------------------------- softmax + cumsums (per row) ---
__global__ __launch_bounds__(256) void k_softmax(
    const float* __restrict__ part, float* __restrict__ ih, float* __restrict__ fh)
{
  const int tid = threadIdx.x, lane = tid & 63, w = tid >> 6;
  const int row = blockIdx.x * 4 + w;
  float vi = 0.f, vf = 0.f;
#pragma unroll
  for (int s = 0; s < 8; ++s) {
    vi += part[(size_t)((s << 13) + row) * 128 + lane];
    vf += part[(size_t)((s << 13) + row) * 128 + 64 + lane];
  }
  float mi = vi, mf = vf;
#pragma unroll
  for (int d = 1; d < 64; d <<= 1) {
    mi = fmaxf(mi, __shfl_xor(mi, d, 64));
    mf = fmaxf(mf, __shfl_xor(mf, d, 64));
  }
  float ei = __expf(vi - mi), ef = __expf(vf - mf);
  float si = ei, sf = ef;
#pragma unroll
  for (int d = 1; d < 64; d <<= 1) {
    si += __shfl_xor(si, d, 64);
    sf += __shfl_xor(sf, d, 64);
  }
  float pi = ei / si, pf = ef / sf;
  float ci = pi, cf = pf;
#pragma unroll
  for (int d = 1; d < 64; d <<= 1) {
    float t = __shfl_up(ci, d, 64); if (lane >= d) ci += t;
    float u = __shfl_up(cf, d, 64); if (lane >= d) cf += u;
  }
  ih[(row << 6) + lane] = 1.0f - (ci - pi);
  fh[(row << 6) + lane] = cf;
}

// -------------------------------------- main gates GEMM + fused epilogue ---
// r11 structure (256x128 tile, 8 waves, 3-slot 72KB LDS, 2 blocks/CU,
// cm-fast XCD map, vmcnt(3) ledger, NO setprio, coalesced epilogue) with
// ONE change: wave geometry 2Mx4N (128x32 tiles) -> 4Mx2N (64x64 tiles).
// Theory: r11 is LDS-read-bandwidth-bound (208 KB LDS traffic per
// co-resident slice-pair vs 128 B/cyc peak; MFMA needs only 1242 cyc).
// Square 64x64 wave-tiles raise FLOP/LDS-byte 25.6 -> 32 (8 ds_read
// instead of 10 per wave-slice): block-slice reads 80 -> 64 KB (-20%).
// acc stays 4x4 f32x4 = 64 regs -> 4 waves/SIMD + 2 blocks/CU preserved.
__global__ __launch_bounds__(512, 4) void k_gemm_main(
    const u16* __restrict__ Ab, const u16* __restrict__ Wb,
    const float* __restrict__ cprev, const float* __restrict__ ihp,
    const float* __restrict__ fhp, float* __restrict__ out)
{
  __shared__ __align__(16) u16 smem[36864];        // 72 KB; epi reuses 64 KB
  const int tid = threadIdx.x, lane = tid & 63, wid = tid >> 6;
  const int wm = wid >> 1, wn = wid & 1;           // 4M x 2N wave grid
  const int c16 = lane & 15, r16 = lane >> 4;

  // cm-FAST XCD swizzle (r3/r9-proven): 1024 blocks = 8 XCD x 128 =
  // 4 rm-panels (A L2-resident) x 32 cm (W streamed, L3-absorbed).
  const int bx = blockIdx.x;
  const int nb = (bx & 7) * 128 + (bx >> 3);
  const int rm = nb >> 5, cm = nb & 31;            // rm slow, cm fast

  // staging: thread -> (row sr=tid>>2, 16B slot slq=tid&3); global source
  // pre-permuted (slq ^ (sr>>1)&3) so linear GLDS dest gets the swizzle.
  const int sr = tid >> 2;                          // 0..127
  const int slq = tid & 3;
  const int xk = (slq ^ ((sr >> 1) & 3)) << 3;
  const u16* pa = Ab + (size_t)(rm * 256 + sr) * 2048 + xk;
  const u16* pb = Wb + (size_t)(cm * 128 + sr) * 2048 + xk;
  char* const ldsW = (char*)smem + (wid << 10);     // wave segment (1 KB)

  // ds_read offsets (u16 elements): slot base + row*32 + swizzled 16B slot.
  const int xsl = (r16 ^ ((c16 >> 1) & 3)) << 3;
  const int base_a = (wm * 64 + c16) * 32 + xsl;        // + i*512 (i=0..3)
  const int base_b = 8192 + (wn * 64 + c16) * 32 + xsl; // + j*512 (j=0..3)

  f32x4 acc[4][4] = {};

#define STAGE3(slice, slot) do {                                       \
    const u16* sa_ = pa + (slice) * 32;                                \
    const u16* sb_ = pb + (slice) * 32;                                \
    char* d_ = ldsW + (slot) * 24576;                                  \
    GLDS(sa_, d_); GLDS(sa_ + 262144, d_ + 8192);                      \
    GLDS(sb_, d_ + 16384);                                             \
  } while (0)

#define SLICE(s, slot, dostage) do {                                   \
    bf16x8 aX[4], bS[4];                                               \
    _Pragma("unroll")                                                  \
    for (int i = 0; i < 4; ++i)                                        \
      aX[i] = *(const bf16x8*)(smem + (slot) * 12288 + base_a + i * 512); \
    _Pragma("unroll")                                                  \
    for (int j = 0; j < 4; ++j)                                        \
      bS[j] = *(const bf16x8*)(smem + (slot) * 12288 + base_b + j * 512); \
    if (dostage) STAGE3(((s) + 2) & 63, ((s) + 2) % 3);                \
    asm volatile("s_waitcnt vmcnt(3)" ::: "memory");                   \
    __builtin_amdgcn_s_barrier();                                      \
    asm volatile("s_waitcnt lgkmcnt(0)" ::: "memory");                 \
    _Pragma("unroll")                                                  \
    for (int i = 0; i < 4; ++i)                                        \
      _Pragma("unroll")                                                \
      for (int j = 0; j < 4; ++j)                                      \
        acc[i][j] = __builtin_amdgcn_mfma_f32_16x16x32_bf16(           \
            aX[i], bS[j], acc[i][j], 0, 0, 0);                         \
    __builtin_amdgcn_s_barrier();                                      \
  } while (0)

  // prologue: slices 0,1 -> slots 0,1; vmcnt(3) forces slice 0 complete
  // (leaves slice 1 in flight); barrier publishes to all waves.
  STAGE3(0, 0); STAGE3(1, 1);
  asm volatile("s_waitcnt vmcnt(3)" ::: "memory");
  __builtin_amdgcn_s_barrier();

  for (int u = 0; u < 21; ++u) {                    // slices 0..62
    const int s0 = u * 3;
    SLICE(s0 + 0, 0, 1);
    SLICE(s0 + 1, 1, 1);
    SLICE(s0 + 2, 2, 1);
  }
  SLICE(63, 0, 0);                                  // peeled last slice
#undef SLICE
#undef STAGE3

  // drain wrap-dummy stages before LDS reuse
  asm volatile("s_waitcnt vmcnt(0)" ::: "memory");
  __builtin_amdgcn_s_barrier();

  // ---- fused ON-LSTM epilogue: 2 row-passes, epi = f32[128][128] (64 KB).
  // Pass p covers tile rows p*128..p*128+127 = waves with wm>>1 == p
  // (wave rows: (wm&1)*64 + i*16 + r16*4 + r; cols: wn*64 + j*16 + c16).
  // Consumer: each thread computes 4 consecutive hidden units, stores v4f
  // h and c -> 128-B contiguous aligned lines (proven r11, WRITE=64MB).
  float* epi = (float*)smem;
#define EPIPASS(p) do {                                                \
    if ((wm >> 1) == (p)) {                                            \
      _Pragma("unroll")                                                \
      for (int i = 0; i < 4; ++i)                                      \
        _Pragma("unroll")                                              \
        for (int j = 0; j < 4; ++j)                                    \
          _Pragma("unroll")                                            \
          for (int r = 0; r < 4; ++r) {                                \
            float v = acc[i][j][r];                                    \
            v = ((c16 & 3) == 3) ? ftanhf(v) : fsig(v);                \
            epi[((wm & 1) * 64 + i * 16 + r16 * 4 + r) * 128 +         \
                wn * 64 + j * 16 + c16] = v;                           \
          }                                                            \
    }                                                                  \
    __syncthreads();                                                   \
    _Pragma("unroll")                                                  \
    for (int e = 0; e < 2; ++e) {                                      \
      int idx = (e << 9) + tid;                                        \
      int mrow = idx >> 3, q = idx & 7;                                \
      const float* g4 = epi + mrow * 128 + q * 16;                     \
      int rowg = rm * 256 + (p) * 128 + mrow;                          \
      int jgb = cm * 32 + q * 4;                                       \
      int lv = jgb >> 4;                                               \
      float vih = ihp[(rowg << 6) + lv], vfh = fhp[(rowg << 6) + lv];  \
      float wq = vih * vfh;                                            \
      v4f cp4 = *(const v4f*)(cprev + rowg * 1024 + jgb);              \
      float cpv[4] = {cp4.x, cp4.y, cp4.z, cp4.w};                     \
      v4f hv, cv;                                                      \
      _Pragma("unroll")                                                \
      for (int t = 0; t < 4; ++t) {                                    \
        v4f g = *(const v4f*)(g4 + t * 4);                             \
        float iv = g.x, fv = g.y, ov = g.z, gv = g.w;                  \
        float cpx = cpv[t];                                            \
        float c = wq * (fv * cpx + iv * gv) + (vfh - wq) * cpx + (vih - wq) * gv; \
        float h = ov * ftanhf(c);                                      \
        hv[t] = h; cv[t] = c;                                          \
      }                                                                \
      *(v4f*)(out + rowg * 1024 + jgb) = hv;                           \
      *(v4f*)(out + 8388608 + rowg * 1024 + jgb) = cv;                 \
    }                                                                  \
    __syncthreads();                                                   \
  } while (0)
  EPIPASS(0); EPIPASS(1);
#undef EPIPASS
}

// -------------------------------------------------------------- launcher ---
extern "C" void kernel_launch(void* const* d_in, const int* in_sizes, int n_in,
                              void* d_out, int out_size, void* d_ws, size_t ws_size,
                              hipStream_t stream) {
  (void)in_sizes; (void)n_in; (void)out_size; (void)ws_size;
  const float* inp   = (const float*)d_in[0];
  const float* hprev = (const float*)d_in[1];
  const float* cprev = (const float*)d_in[2];
  const float* wl    = (const float*)d_in[3];
  const float* wlev  = (const float*)d_in[4];
  float* out = (float*)d_out;
  char* ws = (char*)d_ws;

  u16* Ahi  = (u16*)(ws);
  u16* Alo  = (u16*)(ws + 33554432);
  u16* Whi  = (u16*)(ws + 67108864);
  u16* Wlo  = (u16*)(ws + 84410368);
  float* part = (float*)(ws + 84934656);
  float* ih   = (float*)(ws + 118489088);
  float* fh   = (float*)(ws + 120586240);

  k_convert<<<dim3(2048), dim3(256), 0, stream>>>(inp, hprev, wl, wlev, Ahi, Alo, Whi, Wlo);
  k_gemm_level<<<dim3(64, 8), dim3(256), 0, stream>>>(Ahi, Alo, Whi, Wlo, part);
  k_softmax<<<dim3(2048), dim3(256), 0, stream>>>(part, ih, fh);
  k_gemm_main<<<dim3(1024), dim3(512), 0, stream>>>(Ahi, Whi, cprev, ih, fh, out);
}